// Round 7
// baseline (6325.891 us; speedup 1.0000x reference)
//
#include <hip/hip_runtime.h>
#include <math.h>

// GraphNet: 2x EdgeConv (E=800k, F=H=64) + BN folded/commuted + pooling.
// R7: linearized EdgeConv. Per-node tables P=x@(Wtop-Wbot)+b, Q=x@Wbot
// (node GEMMs), so h1a_edge=relu(P1[dst]+Q1[src]) with NO per-edge GEMM-a,
// and conv2 needs NO edge GEMM at all. pass1=stats only (no LDS), pass2
// rebuilds h1a into MFMA B-frags + GEMM-b + segmax scatter, pass3=pure
// gather+relu+segmax. No h1a spill (ws ~115MB << proven 238MB).

typedef unsigned short u16;
typedef unsigned int   u32;
typedef __bf16 bf16x8 __attribute__((ext_vector_type(8)));
typedef float  f32x4  __attribute__((ext_vector_type(4)));

#define EPSBN 1e-5f
#define PB_TOT 9344
// pblk: 0:stS1a[128] 128:stQ1a[128] 256:stS1b 320:stQ1b 384:stS2 448:stQ2
// 512:s1a[128] 640:t1a[128] 768:b1bF[64] 832:s1b 896:t1b 960:s2 1024:t2
// 1088:gmax[4096] 5184:gsum[4096] 9280:cnt[64]

__device__ __forceinline__ u32 f2bf1(float f){
    u32 u = __float_as_uint(f);
    return (u + 0x7FFFu + ((u >> 16) & 1u)) >> 16;
}
__device__ __forceinline__ float bf2f(u16 b){
    return __uint_as_float(((u32)b) << 16);
}
__device__ __forceinline__ void atomicMaxF(float* a, float v){
    if (v >= 0.f) atomicMax((int*)a, __float_as_int(v));
    else          atomicMin((u32*)a, __float_as_uint(v));
}
// XOR swizzles (pitch 128 / pitch 64) for conflict-free ds_read_b128
__device__ __forceinline__ int swz(int row, int k){
    return row*128 + (k ^ ((row & 7) << 3));
}
__device__ __forceinline__ int swz64(int row, int k){
    return row*64 + (k ^ ((row & 7) << 3));
}
__device__ __forceinline__ f32x4 mfma16(bf16x8 a, bf16x8 b, f32x4 c){
    return __builtin_amdgcn_mfma_f32_16x16x32_bf16(a, b, c, 0, 0, 0);
}

// Segment-run merge masks; ALL shuffles unconditional (R4 lesson).
struct SegMasks { bool head, m1, m2, m4, m8; };
__device__ __forceinline__ SegMasks seg_masks(int dL, int lr){
    int dUp = __shfl_up(dL, 1, 16);
    int d1  = __shfl_down(dL, 1, 16);
    int d2  = __shfl_down(dL, 2, 16);
    int d4  = __shfl_down(dL, 4, 16);
    int d8  = __shfl_down(dL, 8, 16);
    SegMasks s;
    s.head = (lr == 0) || (dUp != dL);
    s.m1 = (lr + 1 < 16) && (d1 == dL);
    s.m2 = (lr + 2 < 16) && (d2 == dL);
    s.m4 = (lr + 4 < 16) && (d4 == dL);
    s.m8 = (lr + 8 < 16) && (d8 == dL);
    return s;
}
__device__ __forceinline__ float seg_max(float v, const SegMasks& s){
    float t1 = __shfl_down(v, 1, 16); if (s.m1) v = fmaxf(v, t1);
    float t2 = __shfl_down(v, 2, 16); if (s.m2) v = fmaxf(v, t2);
    float t4 = __shfl_down(v, 4, 16); if (s.m4) v = fmaxf(v, t4);
    float t8 = __shfl_down(v, 8, 16); if (s.m8) v = fmaxf(v, t8);
    return v;
}

__global__ void k_init(const float* __restrict__ x, u16* __restrict__ xb,
                       float* __restrict__ agg,
                       float* __restrict__ pblk, int* __restrict__ deg,
                       int NF, int N){
    int i = blockIdx.x*256 + threadIdx.x;
    if (i < NF){
        xb[i] = (u16)f2bf1(x[i]);
        agg[i] = -INFINITY;
    }
    if (i < N) deg[i] = 0;
    if (i < PB_TOT){
        pblk[i] = (i >= 1088 && i < 5184) ? -INFINITY : 0.f;
    }
}

__global__ void k_hist(const int* __restrict__ edst, int* __restrict__ deg, int E){
    int e = blockIdx.x*256 + threadIdx.x;
    if (e < E) atomicAdd(&deg[edst[e]], 1);
}

__global__ __launch_bounds__(1024) void k_scan(const int* __restrict__ deg,
                                               int* __restrict__ cursor, int N){
    __shared__ int buf[1024];
    __shared__ int carry;
    int tid = threadIdx.x;
    if (tid == 0) carry = 0;
    __syncthreads();
    for (int base = 0; base < N; base += 1024){
        int i = base + tid;
        int v = (i < N) ? deg[i] : 0;
        buf[tid] = v;
        __syncthreads();
        #pragma unroll
        for (int s = 1; s < 1024; s <<= 1){
            int a = (tid >= s) ? buf[tid - s] : 0;
            __syncthreads();
            buf[tid] += a;
            __syncthreads();
        }
        int inc = buf[tid] + carry;
        if (i < N) cursor[i] = inc - v;
        __syncthreads();
        if (tid == 1023) carry = inc;
        __syncthreads();
    }
}

__global__ void k_scatter(const int* __restrict__ esrc, const int* __restrict__ edst,
                          int* __restrict__ cursor, int2* __restrict__ ep, int E){
    int e = blockIdx.x*256 + threadIdx.x;
    if (e < E){
        int d = edst[e];
        int pos = atomicAdd(&cursor[d], 1);
        ep[pos] = make_int2(esrc[e], d);
    }
}

// Node GEMM: PQ[n][COUT] = xin[n][0:64] @ Wcomb (+bias on first COUT/2 chans)
// Wcomb[k][c] = c<WC ? Wsrc[k][c]-Wsrc[64+k][c] : Wsrc[64+k][c-WC]
template<int COUT>
__global__ __launch_bounds__(256) void k_ngemm(
    const u16* __restrict__ xin, const float* __restrict__ Wsrc,
    const float* __restrict__ bias, float* __restrict__ PQ, int N)
{
    const int WC = COUT/2;
    __shared__ u16 Wt[COUT*64];
    __shared__ u16 At[64*64];
    int tid = threadIdx.x;
    for (int i = tid; i < COUT*64; i += 256){
        int c = i >> 6, k = i & 63;
        float w = (c < WC) ? (Wsrc[k*WC + c] - Wsrc[(64+k)*WC + c])
                           : Wsrc[(64+k)*WC + (c - WC)];
        Wt[swz64(c, k)] = (u16)f2bf1(w);
    }
    int t = blockIdx.x;
    for (int i = tid; i < 512; i += 256){
        int row = i >> 3, ck = i & 7;
        int node = t*64 + row;
        uint4 v;
        if (node < N) v = *(const uint4*)(xin + (size_t)node*64 + ck*8);
        else { v.x = v.y = v.z = v.w = 0u; }
        *(uint4*)&At[swz64(row, ck*8)] = v;
    }
    __syncthreads();
    int lane = tid & 63, wave = tid >> 6;
    int lg = lane >> 4, lr = lane & 15;
    int row = wave*16 + lr;
    bf16x8 bfr[2];
    #pragma unroll
    for (int kt = 0; kt < 2; kt++)
        bfr[kt] = *(const bf16x8*)&At[swz64(row, kt*32 + lg*8)];
    int node = t*64 + wave*16 + lr;
    #pragma unroll
    for (int mt = 0; mt < COUT/16; mt++){
        f32x4 acc = {0.f,0.f,0.f,0.f};
        #pragma unroll
        for (int kt = 0; kt < 2; kt++){
            bf16x8 af = *(const bf16x8*)&Wt[swz64(mt*16 + lr, kt*32 + lg*8)];
            acc = mfma16(af, bfr[kt], acc);
        }
        int ch = mt*16 + lg*4;
        float4 r;
        r.x = acc[0]; r.y = acc[1]; r.z = acc[2]; r.w = acc[3];
        if (ch < WC){
            float4 bb = *(const float4*)(bias + ch);
            r.x += bb.x; r.y += bb.y; r.z += bb.z; r.w += bb.w;
        }
        if (node < N)
            *(float4*)(PQ + (size_t)node*COUT + ch) = r;
    }
}

// pass1: BN1a stats only. h1a = relu(P1[dst]+Q1[src]) (b1a inside P1).
__global__ __launch_bounds__(256) void k_pass1n(
    const float* __restrict__ PQ1, const int2* __restrict__ ep,
    float* __restrict__ pblk, int E, int nTiles)
{
    int tid = threadIdx.x;
    int lane = tid & 63, wave = tid >> 6;
    int lg = lane >> 4, lr = lane & 15;
    float runS[32], runQ[32];
    #pragma unroll
    for (int i = 0; i < 32; i++){ runS[i] = 0.f; runQ[i] = 0.f; }

    for (int t = blockIdx.x; t < nTiles; t += gridDim.x){
        int e = t*64 + wave*16 + lr;
        bool ev = e < E;
        int2 sd = ev ? ep[e] : make_int2(0, 0);
        const float* Pr = PQ1 + (size_t)sd.y*256;
        const float* Qr = PQ1 + (size_t)sd.x*256 + 128;
        #pragma unroll
        for (int kt = 0; kt < 4; kt++){
            int ch = kt*32 + lg*8;
            float4 p0 = *(const float4*)(Pr + ch);
            float4 p1 = *(const float4*)(Pr + ch + 4);
            float4 q0 = *(const float4*)(Qr + ch);
            float4 q1 = *(const float4*)(Qr + ch + 4);
            float h[8];
            h[0] = p0.x + q0.x; h[1] = p0.y + q0.y;
            h[2] = p0.z + q0.z; h[3] = p0.w + q0.w;
            h[4] = p1.x + q1.x; h[5] = p1.y + q1.y;
            h[6] = p1.z + q1.z; h[7] = p1.w + q1.w;
            if (ev){
                #pragma unroll
                for (int j = 0; j < 8; j++){
                    float v = fmaxf(h[j], 0.f);
                    runS[kt*8 + j] += v;
                    runQ[kt*8 + j] = fmaf(v, v, runQ[kt*8 + j]);
                }
            }
        }
    }
    #pragma unroll
    for (int i = 0; i < 32; i++){
        float s = runS[i], q = runQ[i];
        #pragma unroll
        for (int m = 1; m < 16; m <<= 1){ s += __shfl_xor(s, m); q += __shfl_xor(q, m); }
        if (lr == 0){
            int ch = (i >> 3)*32 + lg*8 + (i & 7);
            atomicAdd(&pblk[ch], s);
            atomicAdd(&pblk[128 + ch], q);
        }
    }
}

__global__ void k_fold1(const float* __restrict__ g1a, const float* __restrict__ bt1a,
                        const float* __restrict__ W1b, const float* __restrict__ b1b,
                        float* __restrict__ pblk, float fE)
{
    __shared__ float tS[128];
    int tid = threadIdx.x;
    if (tid < 128){
        float m = pblk[tid] * fE;
        float q = pblk[128 + tid] * fE;
        float v = fmaxf(q - m*m, 0.f);
        float s = g1a[tid] * rsqrtf(v + EPSBN);
        float t = bt1a[tid] - m*s;
        pblk[512 + tid] = s;
        pblk[640 + tid] = t;
        tS[tid] = t;
    }
    __syncthreads();
    if (tid < 64){
        float acc = b1b[tid];
        for (int k = 0; k < 128; k++) acc = fmaf(tS[k], W1b[k*64 + tid], acc);
        pblk[768 + tid] = acc;
    }
}

// pass2: rebuild h1a into MFMA B-frags, GEMM-b (BN1a folded), stats1b,
// segmented-max scatter into agg.
__global__ __launch_bounds__(256) void k_pass2n(
    const float* __restrict__ PQ1, const int2* __restrict__ ep,
    const float* __restrict__ W1b,
    float* __restrict__ pblk, float* __restrict__ agg, int E, int nTiles)
{
    __shared__ u16 Wt2[64*128];   // (s1a * W1b)^T swizzled
    int tid = threadIdx.x;
    for (int i = tid; i < 64*128; i += 256){
        int k = i >> 6, n = i & 63;
        Wt2[swz(n, k)] = (u16)f2bf1(W1b[i] * pblk[512 + k]);
    }
    __syncthreads();
    int lane = tid & 63, wave = tid >> 6;
    int lg = lane >> 4, lr = lane & 15;
    float runS[16], runQ[16], b2r[16];
    #pragma unroll
    for (int i = 0; i < 16; i++){
        runS[i] = 0.f; runQ[i] = 0.f;
        b2r[i] = pblk[768 + (i >> 2)*16 + lg*4 + (i & 3)];
    }

    for (int t = blockIdx.x; t < nTiles; t += gridDim.x){
        int e = t*64 + wave*16 + lr;
        bool ev = e < E;
        int2 sd = ev ? ep[e] : make_int2(0, 0);
        const float* Pr = PQ1 + (size_t)sd.y*256;
        const float* Qr = PQ1 + (size_t)sd.x*256 + 128;
        bf16x8 br2[4];
        #pragma unroll
        for (int kt = 0; kt < 4; kt++){
            int ch = kt*32 + lg*8;
            float4 p0 = *(const float4*)(Pr + ch);
            float4 p1 = *(const float4*)(Pr + ch + 4);
            float4 q0 = *(const float4*)(Qr + ch);
            float4 q1 = *(const float4*)(Qr + ch + 4);
            union { bf16x8 v; u32 u[4]; } cv;
            cv.u[0] = f2bf1(fmaxf(p0.x + q0.x, 0.f)) | (f2bf1(fmaxf(p0.y + q0.y, 0.f)) << 16);
            cv.u[1] = f2bf1(fmaxf(p0.z + q0.z, 0.f)) | (f2bf1(fmaxf(p0.w + q0.w, 0.f)) << 16);
            cv.u[2] = f2bf1(fmaxf(p1.x + q1.x, 0.f)) | (f2bf1(fmaxf(p1.y + q1.y, 0.f)) << 16);
            cv.u[3] = f2bf1(fmaxf(p1.z + q1.z, 0.f)) | (f2bf1(fmaxf(p1.w + q1.w, 0.f)) << 16);
            br2[kt] = cv.v;
        }
        int dL = ev ? sd.y : -2;
        SegMasks sm = seg_masks(dL, lr);
        #pragma unroll
        for (int mt = 0; mt < 4; mt++){
            f32x4 acc = {0.f,0.f,0.f,0.f};
            #pragma unroll
            for (int kt = 0; kt < 4; kt++){
                bf16x8 af = *(const bf16x8*)&Wt2[swz(mt*16 + lr, kt*32 + lg*8)];
                acc = mfma16(af, br2[kt], acc);
            }
            #pragma unroll
            for (int j = 0; j < 4; j++){
                float h = fmaxf(acc[j] + b2r[mt*4 + j], 0.f);
                if (ev){
                    runS[mt*4 + j] += h;
                    runQ[mt*4 + j] = fmaf(h, h, runQ[mt*4 + j]);
                }
                float v = seg_max(h, sm);
                if (sm.head && ev)
                    atomicMaxF(&agg[(size_t)dL*64 + mt*16 + lg*4 + j], v);
            }
        }
    }
    #pragma unroll
    for (int i = 0; i < 16; i++){
        float s = runS[i], q = runQ[i];
        #pragma unroll
        for (int m = 1; m < 16; m <<= 1){ s += __shfl_xor(s, m); q += __shfl_xor(q, m); }
        if (lr == 0){
            int ch = (i >> 2)*16 + lg*4 + (i & 3);
            atomicAdd(&pblk[256 + ch], s);
            atomicAdd(&pblk[320 + ch], q);
        }
    }
}

__global__ void k_fold_st(const float* __restrict__ g, const float* __restrict__ bt,
                          float* __restrict__ pblk, float fE, int so, int qo, int os, int ot)
{
    int tid = threadIdx.x;
    if (tid < 64){
        float m = pblk[so + tid] * fE;
        float q = pblk[qo + tid] * fE;
        float v = fmaxf(q - m*m, 0.f);
        float s = g[tid] * rsqrtf(v + EPSBN);
        pblk[os + tid] = s;
        pblk[ot + tid] = bt[tid] - m*s;
    }
}

__global__ void k_x1(float* __restrict__ agg, const float* __restrict__ pblk,
                     u16* __restrict__ x1b, int NF)
{
    int i = blockIdx.x*256 + threadIdx.x;
    if (i >= NF) return;
    int c = i & 63;
    float a = agg[i];
    float v = (a > -INFINITY) ? fmaf(a, pblk[832 + c], pblk[896 + c]) : 0.f;
    v = fmaxf(v, 0.f);
    x1b[i] = (u16)f2bf1(v);
    agg[i] = -INFINITY;
}

// pass3 (conv2): h2 = relu(P2[dst]+Q2[src]) (b2 inside P2); stats2 + segmax.
__global__ __launch_bounds__(256) void k_pass3n(
    const float* __restrict__ PQ2, const int2* __restrict__ ep,
    float* __restrict__ pblk, float* __restrict__ agg, int E, int nTiles)
{
    int tid = threadIdx.x;
    int lane = tid & 63, wave = tid >> 6;
    int lg = lane >> 4, lr = lane & 15;
    float runS[16], runQ[16];
    #pragma unroll
    for (int i = 0; i < 16; i++){ runS[i] = 0.f; runQ[i] = 0.f; }

    for (int t = blockIdx.x; t < nTiles; t += gridDim.x){
        int e = t*64 + wave*16 + lr;
        bool ev = e < E;
        int2 sd = ev ? ep[e] : make_int2(0, 0);
        const float* Pr = PQ2 + (size_t)sd.y*128 + lg*16;
        const float* Qr = PQ2 + (size_t)sd.x*128 + 64 + lg*16;
        float4 P[4], Q[4];
        #pragma unroll
        for (int u = 0; u < 4; u++){
            P[u] = *(const float4*)(Pr + u*4);
            Q[u] = *(const float4*)(Qr + u*4);
        }
        int dL = ev ? sd.y : -2;
        SegMasks sm = seg_masks(dL, lr);
        #pragma unroll
        for (int u = 0; u < 4; u++){
            float hv[4];
            hv[0] = P[u].x + Q[u].x; hv[1] = P[u].y + Q[u].y;
            hv[2] = P[u].z + Q[u].z; hv[3] = P[u].w + Q[u].w;
            #pragma unroll
            for (int j = 0; j < 4; j++){
                float h = fmaxf(hv[j], 0.f);
                int i = u*4 + j;
                if (ev){
                    runS[i] += h;
                    runQ[i] = fmaf(h, h, runQ[i]);
                }
                float v = seg_max(h, sm);
                if (sm.head && ev)
                    atomicMaxF(&agg[(size_t)dL*64 + lg*16 + i], v);
            }
        }
    }
    #pragma unroll
    for (int i = 0; i < 16; i++){
        float s = runS[i], q = runQ[i];
        #pragma unroll
        for (int m = 1; m < 16; m <<= 1){ s += __shfl_xor(s, m); q += __shfl_xor(q, m); }
        if (lr == 0){
            int ch = lg*16 + i;
            atomicAdd(&pblk[384 + ch], s);
            atomicAdd(&pblk[448 + ch], q);
        }
    }
}

#define FUSE_NODES 128
__global__ __launch_bounds__(256) void k_fuse(const float* __restrict__ agg,
                                              const u16* __restrict__ x1b,
                                              const int* __restrict__ batch,
                                              float* __restrict__ pblk, int N)
{
    int c = threadIdx.x & 63, r = threadIdx.x >> 6;
    int n0 = blockIdx.x*FUSE_NODES + r*(FUSE_NODES/4);
    if (n0 >= N) return;
    int n1 = n0 + FUSE_NODES/4; if (n1 > N) n1 = N;
    float s2c = pblk[960 + c], t2c = pblk[1024 + c];
    float gm = -INFINITY, gs = 0.f;
    int cur = batch[n0], cnt0 = 0;
    for (int n = n0; n < n1; ++n){
        int g = batch[n];
        if (g != cur){
            atomicMaxF(&pblk[1088 + cur*64 + c], gm);
            atomicAdd(&pblk[5184 + cur*64 + c], gs);
            if (c == 0) atomicAdd(&pblk[9280 + cur], (float)cnt0);
            gm = -INFINITY; gs = 0.f; cnt0 = 0; cur = g;
        }
        float a = agg[(size_t)n*64 + c];
        float v = (a > -INFINITY) ? fmaf(a, s2c, t2c) : 0.f;
        v = fmaxf(v, 0.f);
        float f = bf2f(x1b[(size_t)n*64 + c]) + v;
        gm = fmaxf(gm, f); gs += f; cnt0++;
    }
    atomicMaxF(&pblk[1088 + cur*64 + c], gm);
    atomicAdd(&pblk[5184 + cur*64 + c], gs);
    if (c == 0) atomicAdd(&pblk[9280 + cur], (float)cnt0);
}

__global__ void k_out(const float* __restrict__ pblk, float* __restrict__ out)
{
    int i = blockIdx.x*256 + threadIdx.x;
    if (i >= 64*128) return;
    int g = i >> 7, c = i & 127;
    float r;
    if (c < 64){
        float m = pblk[1088 + g*64 + c];
        r = (m > -INFINITY) ? m : 0.f;
    } else {
        float s = pblk[5184 + g*64 + (c - 64)];
        float n = pblk[9280 + g];
        r = s / fmaxf(n, 1.f);
    }
    out[i] = r;
}

extern "C" void kernel_launch(void* const* d_in, const int* in_sizes, int n_in,
                              void* d_out, int out_size, void* d_ws, size_t ws_size,
                              hipStream_t stream)
{
    const float* x    = (const float*)d_in[0];
    const int*   ei   = (const int*)  d_in[1];
    const int*   batch= (const int*)  d_in[2];
    const float* W1a  = (const float*)d_in[3];
    const float* b1a  = (const float*)d_in[4];
    const float* g1a  = (const float*)d_in[5];
    const float* bt1a = (const float*)d_in[6];
    const float* W1b  = (const float*)d_in[7];
    const float* b1b  = (const float*)d_in[8];
    const float* g1b  = (const float*)d_in[9];
    const float* bt1b = (const float*)d_in[10];
    const float* W2   = (const float*)d_in[11];
    const float* b2   = (const float*)d_in[12];
    const float* g2   = (const float*)d_in[13];
    const float* bt2  = (const float*)d_in[14];

    int N  = in_sizes[0] / 64;
    int E  = in_sizes[1] / 2;
    int NF = N * 64;
    int nTiles = (E + 63) / 64;

    char* ws = (char*)d_ws;
    size_t off = 0;
    auto alloc = [&](size_t bytes){ size_t o = off; off += (bytes + 255) & ~(size_t)255; return o; };
    u16*   xb    = (u16*)  (ws + alloc((size_t)NF*2));
    u16*   x1b   = (u16*)  (ws + alloc((size_t)NF*2));
    float* agg   = (float*)(ws + alloc((size_t)NF*4));
    float* pblk  = (float*)(ws + alloc((size_t)PB_TOT*4));
    int*   deg   = (int*)  (ws + alloc((size_t)N*4));
    int*   cursor= (int*)  (ws + alloc((size_t)N*4));
    int2*  ep    = (int2*) (ws + alloc((size_t)E*8));
    float* PQ1   = (float*)(ws + alloc((size_t)N*256*4));
    float* PQ2   = (float*)(ws + alloc((size_t)N*128*4));
    (void)ws_size;

    const int* esrc = ei;
    const int* edst = ei + E;
    int gPass  = nTiles < 2048 ? nTiles : 2048;
    int gElem  = (NF + 255) / 256;
    int gEdge  = (E + 255) / 256;
    int gNode  = (N + 63) / 64;
    float fE   = 1.f / (float)E;

    k_init      <<<gElem, 256, 0, stream>>>(x, xb, agg, pblk, deg, NF, N);
    k_hist      <<<gEdge, 256, 0, stream>>>(edst, deg, E);
    k_scan      <<<1, 1024, 0, stream>>>(deg, cursor, N);
    k_scatter   <<<gEdge, 256, 0, stream>>>(esrc, edst, cursor, ep, E);
    k_ngemm<256><<<gNode, 256, 0, stream>>>(xb, W1a, b1a, PQ1, N);
    k_pass1n    <<<gPass, 256, 0, stream>>>(PQ1, ep, pblk, E, nTiles);
    k_fold1     <<<1, 128, 0, stream>>>(g1a, bt1a, W1b, b1b, pblk, fE);
    k_pass2n    <<<gPass, 256, 0, stream>>>(PQ1, ep, W1b, pblk, agg, E, nTiles);
    k_fold_st   <<<1, 64, 0, stream>>>(g1b, bt1b, pblk, fE, 256, 320, 832, 896);
    k_x1        <<<gElem, 256, 0, stream>>>(agg, pblk, x1b, NF);
    k_ngemm<128><<<gNode, 256, 0, stream>>>(x1b, W2, b2, PQ2, N);
    k_pass3n    <<<gPass, 256, 0, stream>>>(PQ2, ep, pblk, agg, E, nTiles);
    k_fold_st   <<<1, 64, 0, stream>>>(g2, bt2, pblk, fE, 384, 448, 960, 1024);
    k_fuse      <<<(N + FUSE_NODES - 1)/FUSE_NODES, 256, 0, stream>>>(agg, x1b, batch, pblk, N);
    k_out       <<<32, 256, 0, stream>>>(pblk, (float*)d_out);
}